// Round 7
// baseline (39.096 us; speedup 1.0000x reference)
//
#include <hip/hip_runtime.h>
#include <stdint.h>

#define NUM_BBOX    2
#define NUM_CLASSES 20
#define NUM_GRID    7
#define BATCH       64
#define NCELL  (BATCH * NUM_GRID * NUM_GRID)   // 3136
#define NCAND  (NCELL * NUM_BBOX)              // 6272
#define NGROUP (BATCH * NUM_CLASSES)           // 1280
#define CPB    49                              // cells per batch
#define KPB    98                              // candidates per batch
#define NJT    8
#define JTILE  (NCAND / NJT)                   // 784 = 16*49

// ---- workspace layout (bytes) ----
#define WS_SCORE     0         // f32[6272]            25088
#define WS_CELLBOX   25088     // f32[3136*4]          50176
#define WS_CELLLAB   75264     // f32[3136]            12544
#define WS_KEYS      87808     // u64[6272]            50176
#define WS_KEEP      137984    // f32[6272]            25088
#define WS_RANK      163072    // u32[6272]            25088
#define WS_DONE      188160    // u32[98]                392

// monotone float -> sortable u32 (ascending float == ascending u32)
__device__ __forceinline__ unsigned fkey(float f) {
    unsigned u = __float_as_uint(f);
    return (u & 0x80000000u) ? ~u : (u | 0x80000000u);
}

__device__ __forceinline__ float iou_rn(float4 a, float4 b) {
    float xx1 = fmaxf(a.x, b.x), yy1 = fmaxf(a.y, b.y);
    float xx2 = fminf(a.z, b.z), yy2 = fminf(a.w, b.w);
    float w = fmaxf(__fsub_rn(xx2, xx1), 0.0f);
    float h = fmaxf(__fsub_rn(yy2, yy1), 0.0f);
    float inter = __fmul_rn(w, h);
    float aa = __fmul_rn(__fsub_rn(a.z, a.x), __fsub_rn(a.w, a.y));
    float ab = __fmul_rn(__fsub_rn(b.z, b.x), __fsub_rn(b.w, b.y));
    float denom = __fadd_rn(__fsub_rn(__fadd_rn(aa, ab), inter), 1e-9f);
    return __fdiv_rn(inter, denom);
}

// One single-wave block per (batch,label) group. Each block redundantly
// decodes its batch's 49 cells (cheap), label-1 blocks publish the shared
// globals + zero rank/done, every block NMS-es its own group and writes
// keep for exactly its own label's candidates (disjoint-complete).
__global__ void __launch_bounds__(64) k_decode_nms(
        const float* __restrict__ in,
        float* __restrict__ score,
        float* __restrict__ cellBox,
        float* __restrict__ cellLabel,
        unsigned long long* __restrict__ keys,
        float* __restrict__ keepOrig,
        unsigned* __restrict__ rank,
        unsigned* __restrict__ done) {
    __shared__ float2 raw2[1225];                 // 49*50 floats
    __shared__ unsigned long long lkey[KPB];
    __shared__ float  lscore[KPB];
    __shared__ float4 lbox[CPB];
    __shared__ int    llab[CPB];
    __shared__ float  lkeep[KPB];
    __shared__ unsigned long long mkey[KPB];
    __shared__ unsigned long long skey[KPB];

    const int g    = blockIdx.x;
    const int b    = g / NUM_CLASSES;
    const int L    = g % NUM_CLASSES + 1;
    const int lane = (int)threadIdx.x;
    const int base = b * KPB;

    const float2* src = (const float2*)(in + b * (CPB * 50));
    for (int i = lane; i < 1225; i += 64) raw2[i] = src[i];
    lkeep[lane] = 0.0f;
    if (lane + 64 < KPB) lkeep[lane + 64] = 0.0f;
    __syncthreads();

    if (lane < CPB) {
        const float* p = (const float*)raw2 + lane * 50;
        int r = lane / NUM_GRID, c = lane % NUM_GRID;

        float sc[NUM_BBOX];
        for (int bb = 0; bb < NUM_BBOX; ++bb) {
            const float* q = p + bb * 25;
            float conf = q[4];
            float m = __fmul_rn(q[5], conf);
            for (int k = 1; k < NUM_CLASSES; ++k)
                m = fmaxf(m, __fmul_rn(q[5 + k], conf));
            sc[bb] = m;
        }
        int best = (sc[1] > sc[0]) ? 1 : 0;       // first-occurrence argmax
        const float* q = p + best * 25;

        int lab = 0; float bv = q[5];
        for (int k = 1; k < NUM_CLASSES; ++k)
            if (q[5 + k] > bv) { bv = q[5 + k]; lab = k; }

        float x  = __fdiv_rn(__fadd_rn(q[0], (float)r), 7.0f);
        float y  = __fdiv_rn(__fadd_rn(q[1], (float)c), 7.0f);
        float hw = __fmul_rn(q[2], 0.5f);
        float hh = __fmul_rn(q[3], 0.5f);
        float4 bx = make_float4(__fsub_rn(x, hw), __fsub_rn(y, hh),
                                __fadd_rn(x, hw), __fadd_rn(y, hh));
        lbox[lane] = bx;
        llab[lane] = lab + 1;
        for (int bb = 0; bb < NUM_BBOX; ++bb) {
            float s = sc[bb];
            bool valid = s > 0.5f;
            float kf = valid ? -s : __builtin_inff();
            int t = lane * 2 + bb;
            lkey[t]   = ((unsigned long long)fkey(kf) << 32) | (unsigned)(base + t);
            lscore[t] = s;
        }
    }
    __syncthreads();

    if (L == 1) {                                  // publisher block for batch b
        if (lane < CPB) {
            int cell = b * CPB + lane;
            *(float4*)(cellBox + cell * 4) = lbox[lane];
            cellLabel[cell] = (float)llab[lane];
        }
        keys[base + lane]  = lkey[lane];
        score[base + lane] = lscore[lane];
        rank[base + lane]  = 0u;
        if (lane + 64 < KPB) {
            keys[base + lane + 64]  = lkey[lane + 64];
            score[base + lane + 64] = lscore[lane + 64];
            rank[base + lane + 64]  = 0u;
        }
        if (b == 0) {
            done[lane] = 0u;
            if (lane + 64 < KPB) done[lane + 64] = 0u;
        }
    }

    // ---- NMS for group (b, L) ----
    unsigned long long key0 = lkey[lane];
    int lab0 = llab[lane >> 1];
    bool v0 = ((unsigned)(key0 >> 32) < 0x80000000u) && (lab0 == L);
    unsigned long long key1 = 0; bool v1 = false; int lab1 = -1;
    if (lane + 64 < KPB) {
        key1 = lkey[lane + 64];
        lab1 = llab[(lane + 64) >> 1];
        v1 = ((unsigned)(key1 >> 32) < 0x80000000u) && (lab1 == L);
    }
    unsigned long long b0 = __ballot(v0);
    unsigned long long b1 = __ballot(v1);
    int n0 = __popcll(b0);
    int n  = n0 + __popcll(b1);
    unsigned long long below = (1ull << lane) - 1ull;
    if (v0) mkey[__popcll(b0 & below)] = key0;
    if (v1) mkey[n0 + __popcll(b1 & below)] = key1;
    __syncthreads();

    if (n > 0) {
        for (int s = 0; s < 2; ++s) {
            int j = lane + s * 64;
            if (j < n) {
                unsigned long long kj = mkey[j];
                int rr = 0;
                for (int i2 = 0; i2 < n; ++i2) rr += (mkey[i2] < kj) ? 1 : 0;
                skey[rr] = kj;                     // rank-by-count == stable sort
            }
        }
    }
    __syncthreads();

    if (n > 0) {
        float4 box0 = make_float4(0.f, 0.f, 0.f, 0.f), box1 = box0;
        int t0 = 0, t1 = 0, keep0 = 0, keep1 = 0;
        if (lane < n) {
            t0 = (int)(unsigned)skey[lane] - base;
            box0 = lbox[t0 >> 1];
            keep0 = 1;
        }
        if (lane + 64 < n) {
            t1 = (int)(unsigned)skey[lane + 64] - base;
            box1 = lbox[t1 >> 1];
            keep1 = 1;
        }
        for (int i = 0; i < n; ++i) {
            int srcl = i & 63;
            int ki = __shfl((i < 64) ? keep0 : keep1, srcl);
            if (ki) {
                float4 s4 = (i < 64) ? box0 : box1;
                float4 bi;
                bi.x = __shfl(s4.x, srcl);
                bi.y = __shfl(s4.y, srcl);
                bi.z = __shfl(s4.z, srcl);
                bi.w = __shfl(s4.w, srcl);
                if (keep0 && lane > i)      { if (iou_rn(bi, box0) > 0.3f) keep0 = 0; }
                if (keep1 && lane + 64 > i) { if (iou_rn(bi, box1) > 0.3f) keep1 = 0; }
            }
        }
        if (keep0) lkeep[t0] = 1.0f;
        if (keep1) lkeep[t1] = 1.0f;
    }
    __syncthreads();

    // keep for exactly this block's label (disjoint-complete across blocks)
    if (lab0 == L) keepOrig[base + lane] = lkeep[lane];
    if (lane + 64 < KPB && lab1 == L) keepOrig[base + lane + 64] = lkeep[lane + 64];
}

// 98 x 8 blocks x 64 threads. Block (ib, jt): stage j-chunk into LDS,
// count keys[j] < keys[i] via broadcast ds_reads, atomicAdd partial into
// rank[i]. The 8th finisher per ib (device-scope done counter) re-reads
// the completed ranks atomically and scatters all outputs.
__global__ void __launch_bounds__(64) k_rank_scatter(
        const unsigned long long* __restrict__ keys,
        const float* __restrict__ score,
        const float* __restrict__ cellBox,
        const float* __restrict__ cellLabel,
        const float* __restrict__ keepOrig,
        unsigned* __restrict__ rank,
        unsigned* __restrict__ done,
        float* __restrict__ out) {
    __shared__ unsigned long long t[JTILE];       // 6272 B
    const int lane = (int)threadIdx.x;
    const int ib   = (int)blockIdx.x;             // 0..97
    const int i    = ib * 64 + lane;
    const int j0   = (int)blockIdx.y * JTILE;

    unsigned long long my = keys[i];
    for (int j = lane; j < JTILE; j += 64) t[j] = keys[j0 + j];
    __syncthreads();

    unsigned r = 0;
    #pragma unroll 16
    for (int j = 0; j < JTILE; ++j)
        r += (t[j] < my) ? 1u : 0u;
    atomicAdd(&rank[i], r);
    __threadfence();

    int old = 0;
    if (lane == 0) old = (int)atomicAdd(&done[ib], 1u);
    old = __shfl(old, 0);
    if (old == NJT - 1) {                         // last finisher for this ib
        __threadfence();
        unsigned rr = atomicAdd(&rank[i], 0u);    // atomic read: all 8 partials
        int cell = i >> 1;
        out[rr] = (float)(i / 98);                // batch id
        float4 bx = *(const float4*)(cellBox + cell * 4);
        *(float4*)(out + NCAND + rr * 4) = bx;
        out[NCAND * 5 + rr] = cellLabel[cell];
        out[NCAND * 6 + rr] = score[i];
        out[NCAND * 7 + rr] = keepOrig[i];
    }
}

extern "C" void kernel_launch(void* const* d_in, const int* in_sizes, int n_in,
                              void* d_out, int out_size, void* d_ws, size_t ws_size,
                              hipStream_t stream) {
    const float* in = (const float*)d_in[0];
    char* ws = (char*)d_ws;
    float*              score     = (float*)(ws + WS_SCORE);
    float*              cellBox   = (float*)(ws + WS_CELLBOX);
    float*              cellLabel = (float*)(ws + WS_CELLLAB);
    unsigned long long* keys      = (unsigned long long*)(ws + WS_KEYS);
    float*              keepOrig  = (float*)(ws + WS_KEEP);
    unsigned*           rank      = (unsigned*)(ws + WS_RANK);
    unsigned*           done      = (unsigned*)(ws + WS_DONE);
    float* out = (float*)d_out;

    k_decode_nms<<<NGROUP, 64, 0, stream>>>(in, score, cellBox, cellLabel,
                                            keys, keepOrig, rank, done);
    k_rank_scatter<<<dim3(NCAND / 64, NJT), 64, 0, stream>>>(
        keys, score, cellBox, cellLabel, keepOrig, rank, done, out);
}